// Round 1
// 851.390 us; speedup vs baseline: 1.1621x; 1.1621x over previous
//
#include <hip/hip_runtime.h>
#include <hip/hip_bf16.h>

// TFSwinSelfAttention fused kernel for MI355X (gfx950).
// Shapes: B=4096 windows, N=49 tokens, D=256 = 8 heads x 32.
// fp32 in/out; internal bf16 MFMA compute (fp32 accum) within harness tol.
//
// Round-3 revision (occupancy attack):
//   Previous: 57,344 B LDS/block -> 2 blocks/CU -> 1 wave/SIMD -> all
//   latencies exposed (MfmaUtil 6.4%, VALUBusy 12.9%, Occ 12.1%).
//   Change 1: P[64][72] (9,216 B) OVERLAYS q+k (10,240 B) in a union —
//     q/k are dead once the score fragments are in registers, and every
//     P value is dataflow-dependent on those fragments, so within-wave
//     DS ordering (lgkmcnt, alias-conservative codegen on the union)
//     guarantees correctness. Per-wave LDS 24,064 -> 14,848 B.
//     Block LDS 57,170 -> 38,738 B -> 4 blocks/CU -> 2 waves/SIMD.
//   Change 2: remove the three per-head __syncthreads() — each wave only
//     touches its own WaveBuf after the one-time staging barrier; the
//     barriers needlessly phase-locked the two waves. One inline
//     s_waitcnt lgkmcnt(0) (+ "memory" clobber) after the PV fragment
//     reads fences the only write-after-read hazard that is NOT
//     dataflow-protected (next head's projection stores vs this head's
//     P/vt reads).
//
// kernel 0: repack wq/wk/wv [256x256] fp32 -> bf16 MFMA-B-fragment order
//           (384KB in d_ws); L2-resident, shared by all 4096 blocks.
// kernel 1: 1 block = 1 window, 128 threads = 2 waves, wave w does heads
//           {w, w+2, w+4, w+6}.

typedef __bf16 bf16;
typedef __attribute__((ext_vector_type(8))) __bf16 bf16x8;
typedef __attribute__((ext_vector_type(4))) float f32x4;

__device__ __forceinline__ f32x4 mfma16(bf16x8 a, bf16x8 b, f32x4 c) {
    return __builtin_amdgcn_mfma_f32_16x16x32_bf16(a, b, c, 0, 0, 0);
}

__device__ __forceinline__ bf16x8 cvt8(const float* __restrict__ p) {
    f32x4 lo = *(const f32x4*)p;
    f32x4 hi = *(const f32x4*)(p + 4);
    bf16x8 r;
    r[0] = (bf16)lo[0]; r[1] = (bf16)lo[1]; r[2] = (bf16)lo[2]; r[3] = (bf16)lo[3];
    r[4] = (bf16)hi[0]; r[5] = (bf16)hi[1]; r[6] = (bf16)hi[2]; r[7] = (bf16)hi[3];
    return r;
}

// --------------------------------------------------------------------------
// Kernel 0: repack fp32 weights into bf16 B-fragment order.
// packed[((t*16 + nt)*8 + kk)*512 + L*8 + j] = W_t[kk*32 + (L>>4)*8 + j][nt*16 + (L&15)]
__global__ void repack_w(const float* __restrict__ wq, const float* __restrict__ wk,
                         const float* __restrict__ wv, bf16* __restrict__ pk) {
    int i = blockIdx.x * 256 + threadIdx.x;      // 0 .. 3*65536-1
    int t = i >> 16;
    int r = i & 65535;
    int kr = r >> 8, nc = r & 255;
    const float* w = (t == 0) ? wq : (t == 1) ? wk : wv;
    int nt = nc >> 4;
    int kk = kr >> 5;
    int Ln = (((kr >> 3) & 3) << 4) | (nc & 15);
    int j  = kr & 7;
    pk[(((t * 16 + nt) * 8 + kk) << 9) + Ln * 8 + j] = (bf16)w[r];
}

// --------------------------------------------------------------------------
#define NTOK 49
#define SCALE 0.17677669529663687f   // 1/sqrt(32)

struct __align__(16) WaveBuf {
    union {
        struct {
            bf16 q[64 * 40];    // 5120 B
            bf16 k[64 * 40];    // 5120 B
        } qk;
        bf16 P[64 * 72];        // 9216 B — overlays q+k (dead by then)
    } u;
    bf16 vt[32 * 72];           // 4608 B  (transposed: [dim][token])
};                              // 14,848 B per wave

__global__ __launch_bounds__(128, 2) void swin_attn(
    const float* __restrict__ hidden, const float* __restrict__ mask_g,
    const float* __restrict__ bq_g, const float* __restrict__ bk_g,
    const float* __restrict__ bv_g, const float* __restrict__ table_g,
    const bf16* __restrict__ pkw, float* __restrict__ out)
{
    __shared__ WaveBuf wb[2];       // 29,696 B
    __shared__ bf16 maskL[2401];    //  4,802 B
    __shared__ bf16 tabL[1352];     //  2,704 B
    __shared__ bf16 biasL[768];     //  1,536 B  => 38,738 B total -> 4 blocks/CU

    const int tid  = threadIdx.x;
    const int b    = blockIdx.x;
    const int widx = b & 63;

    // ---- cooperative staging (fp32 -> bf16) ----------------------------
    for (int i = tid; i < 2401; i += 128) maskL[i] = (bf16)mask_g[widx * 2401 + i];
    for (int i = tid; i < 1352; i += 128) tabL[i]  = (bf16)table_g[i];
    for (int i = tid; i < 256;  i += 128) {
        biasL[i]       = (bf16)bq_g[i];
        biasL[256 + i] = (bf16)bk_g[i];
        biasL[512 + i] = (bf16)bv_g[i];
    }
    __syncthreads();   // the ONLY block-wide barrier: shared ro-staging ready

    const int wave = tid >> 6;
    const int L    = tid & 63;
    const int quad = L >> 4;
    const int cc   = L & 15;
    WaveBuf& W = wb[wave];
    const float* hbase = hidden + (size_t)b * (NTOK * 256);

    // ---- geometry: rel-pos linear coords per lane ----------------------
    int pr[16];
#pragma unroll
    for (int mt = 0; mt < 4; ++mt)
#pragma unroll
        for (int j = 0; j < 4; ++j) {
            int r = 16 * mt + 4 * quad + j;
            int rh = (r * 9363) >> 16;          // r / 7 for r < 64
            pr[mt * 4 + j] = 13 * rh + (r - 7 * rh);
        }
    int pc[4];
#pragma unroll
    for (int nt = 0; nt < 4; ++nt) {
        int c = 16 * nt + cc;
        int ch = (c * 9363) >> 16;
        pc[nt] = 13 * ch + (c - 7 * ch);
    }

    // ---- A-fragments of the window: head-invariant, load once ----------
    bf16x8 afr[4][8];
#pragma unroll
    for (int mt = 0; mt < 4; ++mt) {
        int row = 16 * mt + cc;
        if (row > 48) row = 48;                 // clamp: those D-rows are discarded
        const float* rp = hbase + row * 256 + quad * 8;
#pragma unroll
        for (int kk = 0; kk < 8; ++kk)
            afr[mt][kk] = cvt8(rp + kk * 32);
    }

    // ---- per-head pipeline ---------------------------------------------
    for (int hi = 0; hi < 4; ++hi) {
        const int h = wave + 2 * hi;

        // ---- QKV projection: x[64x256] @ W[256 x (2x16 cols)] ----------
#pragma unroll
        for (int t = 0; t < 3; ++t)
#pragma unroll
            for (int hf = 0; hf < 2; ++hf) {
                const int ntg = h * 2 + hf;
                const bf16* bp = pkw + (((t * 16 + ntg) * 8) << 9) + L * 8;
                f32x4 acc[4];
#pragma unroll
                for (int mt = 0; mt < 4; ++mt) acc[mt] = (f32x4){0.f, 0.f, 0.f, 0.f};
#pragma unroll
                for (int kk = 0; kk < 8; ++kk) {
                    bf16x8 bfv = *(const bf16x8*)(bp + (kk << 9));
#pragma unroll
                    for (int mt = 0; mt < 4; ++mt)
                        acc[mt] = mfma16(afr[mt][kk], bfv, acc[mt]);
                }
                const float bias = (float)biasL[t * 256 + h * 32 + hf * 16 + cc];
                const int d = hf * 16 + cc;
#pragma unroll
                for (int mt = 0; mt < 4; ++mt)
#pragma unroll
                    for (int j = 0; j < 4; ++j) {
                        int row = 16 * mt + 4 * quad + j;   // D layout: row=(lane>>4)*4+reg
                        bf16 val = (bf16)(acc[mt][j] + bias);
                        if (t == 0)      W.u.qk.q[row * 40 + d] = val;
                        else if (t == 1) W.u.qk.k[row * 40 + d] = val;
                        else             W.vt[d * 72 + row] = val;
                    }
            }
        // no barrier: this wave's own buffers; lgkmcnt orders write->read

        // ---- scores S = q @ k^T  (K=32, one mfma per 16x16 tile) -------
        f32x4 s[4][4];
        {
            bf16x8 aq[4], bkf[4];
#pragma unroll
            for (int mt = 0; mt < 4; ++mt)
                aq[mt] = *(const bf16x8*)(&W.u.qk.q[(16 * mt + cc) * 40 + quad * 8]);
#pragma unroll
            for (int nt = 0; nt < 4; ++nt)
                bkf[nt] = *(const bf16x8*)(&W.u.qk.k[(16 * nt + cc) * 40 + quad * 8]);
            const f32x4 z = (f32x4){0.f, 0.f, 0.f, 0.f};
#pragma unroll
            for (int mt = 0; mt < 4; ++mt)
#pragma unroll
                for (int nt = 0; nt < 4; ++nt)
                    s[mt][nt] = mfma16(aq[mt], bkf[nt], z);
        }

        // ---- softmax (row r in lanes [16*quad .. 16*quad+15]) ----------
        // P overwrites q/k storage; every P value depends on all score
        // fragments, so the overwrite is dataflow-ordered after the reads.
        float linv[4][4];
#pragma unroll
        for (int mt = 0; mt < 4; ++mt)
#pragma unroll
            for (int j = 0; j < 4; ++j) {
                const int r = 16 * mt + 4 * quad + j;
                float vals[4];
#pragma unroll
                for (int nt = 0; nt < 4; ++nt) {
                    const int c = 16 * nt + cc;
                    float sc = s[mt][nt][j] * SCALE;
                    if (r < 49 && c < 49) {
                        int idx = pr[mt * 4 + j] - pc[nt] + 84;
                        sc += (float)tabL[idx * 8 + h] + (float)maskL[r * 49 + c];
                    } else {
                        sc = -1e30f;
                    }
                    vals[nt] = sc;
                }
                float mx = fmaxf(fmaxf(vals[0], vals[1]), fmaxf(vals[2], vals[3]));
                mx = fmaxf(mx, __shfl_xor(mx, 1));
                mx = fmaxf(mx, __shfl_xor(mx, 2));
                mx = fmaxf(mx, __shfl_xor(mx, 4));
                mx = fmaxf(mx, __shfl_xor(mx, 8));
                float sum = 0.f;
#pragma unroll
                for (int nt = 0; nt < 4; ++nt) {
                    float e = __expf(vals[nt] - mx);   // masked cols: exp(-1e30)=0
                    sum += e;
                    W.u.P[r * 72 + 16 * nt + cc] = (bf16)e;
                }
                sum += __shfl_xor(sum, 1);
                sum += __shfl_xor(sum, 2);
                sum += __shfl_xor(sum, 4);
                sum += __shfl_xor(sum, 8);
                linv[mt][j] = 1.0f / sum;
            }
        // no barrier: P/vt are this wave's own; lgkmcnt orders write->read

        // ---- O = P @ v  (K=64 tokens: 2 mfma K-steps) ------------------
        f32x4 o[4][2];
#pragma unroll
        for (int mt = 0; mt < 4; ++mt) {
            o[mt][0] = (f32x4){0.f, 0.f, 0.f, 0.f};
            o[mt][1] = (f32x4){0.f, 0.f, 0.f, 0.f};
        }
#pragma unroll
        for (int kk = 0; kk < 2; ++kk) {
            bf16x8 bvf[2];
#pragma unroll
            for (int nt = 0; nt < 2; ++nt)
                bvf[nt] = *(const bf16x8*)(&W.vt[(16 * nt + cc) * 72 + kk * 32 + quad * 8]);
#pragma unroll
            for (int mt = 0; mt < 4; ++mt) {
                bf16x8 ap = *(const bf16x8*)(&W.u.P[(16 * mt + cc) * 72 + kk * 32 + quad * 8]);
                o[mt][0] = mfma16(ap, bvf[0], o[mt][0]);
                o[mt][1] = mfma16(ap, bvf[1], o[mt][1]);
            }
        }
        // Fence the one non-dataflow-protected hazard: next head's
        // projection ds_writes (q/k/vt) must not pass this head's P/vt
        // ds_reads. "memory" clobber blocks compile-time motion; the
        // waitcnt drains at runtime (~free: MFMAs above already consumed).
        asm volatile("s_waitcnt lgkmcnt(0)" ::: "memory");

        // ---- epilogue: normalize (fp32) + store fp32 -------------------
        float* op = out + (size_t)b * (NTOK * 256) + h * 32;
#pragma unroll
        for (int mt = 0; mt < 4; ++mt)
#pragma unroll
            for (int j = 0; j < 4; ++j) {
                const int r = 16 * mt + 4 * quad + j;
                if (r < 49) {
                    op[(size_t)r * 256 + 0 * 16 + cc] = o[mt][0][j] * linv[mt][j];
                    op[(size_t)r * 256 + 1 * 16 + cc] = o[mt][1][j] * linv[mt][j];
                }
            }
    }
}

// --------------------------------------------------------------------------
extern "C" void kernel_launch(void* const* d_in, const int* in_sizes, int n_in,
                              void* d_out, int out_size, void* d_ws, size_t ws_size,
                              hipStream_t stream) {
    const float* hidden = (const float*)d_in[0];   // [4096,49,256]
    const float* mask   = (const float*)d_in[1];   // [64,49,49]
    const float* wq     = (const float*)d_in[2];   // [256,256]
    const float* bq     = (const float*)d_in[3];   // [256]
    const float* wk     = (const float*)d_in[4];
    const float* bk     = (const float*)d_in[5];
    const float* wv     = (const float*)d_in[6];
    const float* bv     = (const float*)d_in[7];
    const float* tab    = (const float*)d_in[8];   // [169,8]
    float* out = (float*)d_out;
    bf16* pkw = (bf16*)d_ws;                       // 393,216 B of repacked bf16 weights

    repack_w<<<768, 256, 0, stream>>>(wq, wk, wv, pkw);
    swin_attn<<<4096, 128, 0, stream>>>(hidden, mask, bq, bk, bv, tab, pkw, out);
}

// Round 2
// 846.570 us; speedup vs baseline: 1.1687x; 1.0057x over previous
//
#include <hip/hip_runtime.h>
#include <hip/hip_bf16.h>

// TFSwinSelfAttention fused kernel for MI355X (gfx950).
// Shapes: B=4096 windows, N=49 tokens, D=256 = 8 heads x 32.
// fp32 in/out; internal bf16 MFMA compute (fp32 accum) within harness tol.
//
// Round-4 revision (kill the spill):
//   Round-3 used __launch_bounds__(128, 2); the backend squeezed VGPRs to
//   128 (the 4-waves/SIMD step) by spilling the 128-VGPR afr[] A-fragment
//   cache to scratch — even though LDS (38.9 KB -> 4 blocks/CU) caps
//   occupancy at 2 waves/SIMD regardless. Counters: WRITE_SIZE +132 MB
//   (spill stores), FETCH_SIZE +240 MB (spill reloads) vs round-2.
//   Fix: amdgpu_waves_per_eu(2,2) pins the occupancy target at exactly
//   2 waves/EU -> 256-VGPR budget -> afr stays in registers, zero scratch.
//   LDS layout unchanged: 38,738 B/block -> 4 blocks/CU -> 2 waves/SIMD.
//
// Carried from round-3:
//   - P[64][72] overlays q+k in a union (dead by softmax; dataflow-ordered).
//   - No per-head __syncthreads(): per-wave buffers, single staging barrier;
//     one inline s_waitcnt lgkmcnt(0) fences the next-head WAR hazard.
//
// kernel 0: repack wq/wk/wv [256x256] fp32 -> bf16 MFMA-B-fragment order
//           (384KB in d_ws); L2-resident, shared by all 4096 blocks.
// kernel 1: 1 block = 1 window, 128 threads = 2 waves, wave w does heads
//           {w, w+2, w+4, w+6}.

typedef __bf16 bf16;
typedef __attribute__((ext_vector_type(8))) __bf16 bf16x8;
typedef __attribute__((ext_vector_type(4))) float f32x4;

__device__ __forceinline__ f32x4 mfma16(bf16x8 a, bf16x8 b, f32x4 c) {
    return __builtin_amdgcn_mfma_f32_16x16x32_bf16(a, b, c, 0, 0, 0);
}

__device__ __forceinline__ bf16x8 cvt8(const float* __restrict__ p) {
    f32x4 lo = *(const f32x4*)p;
    f32x4 hi = *(const f32x4*)(p + 4);
    bf16x8 r;
    r[0] = (bf16)lo[0]; r[1] = (bf16)lo[1]; r[2] = (bf16)lo[2]; r[3] = (bf16)lo[3];
    r[4] = (bf16)hi[0]; r[5] = (bf16)hi[1]; r[6] = (bf16)hi[2]; r[7] = (bf16)hi[3];
    return r;
}

// --------------------------------------------------------------------------
// Kernel 0: repack fp32 weights into bf16 B-fragment order.
// packed[((t*16 + nt)*8 + kk)*512 + L*8 + j] = W_t[kk*32 + (L>>4)*8 + j][nt*16 + (L&15)]
__global__ void repack_w(const float* __restrict__ wq, const float* __restrict__ wk,
                         const float* __restrict__ wv, bf16* __restrict__ pk) {
    int i = blockIdx.x * 256 + threadIdx.x;      // 0 .. 3*65536-1
    int t = i >> 16;
    int r = i & 65535;
    int kr = r >> 8, nc = r & 255;
    const float* w = (t == 0) ? wq : (t == 1) ? wk : wv;
    int nt = nc >> 4;
    int kk = kr >> 5;
    int Ln = (((kr >> 3) & 3) << 4) | (nc & 15);
    int j  = kr & 7;
    pk[(((t * 16 + nt) * 8 + kk) << 9) + Ln * 8 + j] = (bf16)w[r];
}

// --------------------------------------------------------------------------
#define NTOK 49
#define SCALE 0.17677669529663687f   // 1/sqrt(32)

struct __align__(16) WaveBuf {
    union {
        struct {
            bf16 q[64 * 40];    // 5120 B
            bf16 k[64 * 40];    // 5120 B
        } qk;
        bf16 P[64 * 72];        // 9216 B — overlays q+k (dead by then)
    } u;
    bf16 vt[32 * 72];           // 4608 B  (transposed: [dim][token])
};                              // 14,848 B per wave

__global__ __launch_bounds__(128)
__attribute__((amdgpu_waves_per_eu(2, 2)))      // pin 2 waves/EU: 256-VGPR budget, no spill
void swin_attn(
    const float* __restrict__ hidden, const float* __restrict__ mask_g,
    const float* __restrict__ bq_g, const float* __restrict__ bk_g,
    const float* __restrict__ bv_g, const float* __restrict__ table_g,
    const bf16* __restrict__ pkw, float* __restrict__ out)
{
    __shared__ WaveBuf wb[2];       // 29,696 B
    __shared__ bf16 maskL[2401];    //  4,802 B
    __shared__ bf16 tabL[1352];     //  2,704 B
    __shared__ bf16 biasL[768];     //  1,536 B  => 38,738 B total -> 4 blocks/CU

    const int tid  = threadIdx.x;
    const int b    = blockIdx.x;
    const int widx = b & 63;

    // ---- cooperative staging (fp32 -> bf16) ----------------------------
    for (int i = tid; i < 2401; i += 128) maskL[i] = (bf16)mask_g[widx * 2401 + i];
    for (int i = tid; i < 1352; i += 128) tabL[i]  = (bf16)table_g[i];
    for (int i = tid; i < 256;  i += 128) {
        biasL[i]       = (bf16)bq_g[i];
        biasL[256 + i] = (bf16)bk_g[i];
        biasL[512 + i] = (bf16)bv_g[i];
    }
    __syncthreads();   // the ONLY block-wide barrier: shared ro-staging ready

    const int wave = tid >> 6;
    const int L    = tid & 63;
    const int quad = L >> 4;
    const int cc   = L & 15;
    WaveBuf& W = wb[wave];
    const float* hbase = hidden + (size_t)b * (NTOK * 256);

    // ---- geometry: rel-pos linear coords per lane ----------------------
    int pr[16];
#pragma unroll
    for (int mt = 0; mt < 4; ++mt)
#pragma unroll
        for (int j = 0; j < 4; ++j) {
            int r = 16 * mt + 4 * quad + j;
            int rh = (r * 9363) >> 16;          // r / 7 for r < 64
            pr[mt * 4 + j] = 13 * rh + (r - 7 * rh);
        }
    int pc[4];
#pragma unroll
    for (int nt = 0; nt < 4; ++nt) {
        int c = 16 * nt + cc;
        int ch = (c * 9363) >> 16;
        pc[nt] = 13 * ch + (c - 7 * ch);
    }

    // ---- A-fragments of the window: head-invariant, load once ----------
    bf16x8 afr[4][8];
#pragma unroll
    for (int mt = 0; mt < 4; ++mt) {
        int row = 16 * mt + cc;
        if (row > 48) row = 48;                 // clamp: those D-rows are discarded
        const float* rp = hbase + row * 256 + quad * 8;
#pragma unroll
        for (int kk = 0; kk < 8; ++kk)
            afr[mt][kk] = cvt8(rp + kk * 32);
    }

    // ---- per-head pipeline ---------------------------------------------
    for (int hi = 0; hi < 4; ++hi) {
        const int h = wave + 2 * hi;

        // ---- QKV projection: x[64x256] @ W[256 x (2x16 cols)] ----------
#pragma unroll
        for (int t = 0; t < 3; ++t)
#pragma unroll
            for (int hf = 0; hf < 2; ++hf) {
                const int ntg = h * 2 + hf;
                const bf16* bp = pkw + (((t * 16 + ntg) * 8) << 9) + L * 8;
                f32x4 acc[4];
#pragma unroll
                for (int mt = 0; mt < 4; ++mt) acc[mt] = (f32x4){0.f, 0.f, 0.f, 0.f};
#pragma unroll
                for (int kk = 0; kk < 8; ++kk) {
                    bf16x8 bfv = *(const bf16x8*)(bp + (kk << 9));
#pragma unroll
                    for (int mt = 0; mt < 4; ++mt)
                        acc[mt] = mfma16(afr[mt][kk], bfv, acc[mt]);
                }
                const float bias = (float)biasL[t * 256 + h * 32 + hf * 16 + cc];
                const int d = hf * 16 + cc;
#pragma unroll
                for (int mt = 0; mt < 4; ++mt)
#pragma unroll
                    for (int j = 0; j < 4; ++j) {
                        int row = 16 * mt + 4 * quad + j;   // D layout: row=(lane>>4)*4+reg
                        bf16 val = (bf16)(acc[mt][j] + bias);
                        if (t == 0)      W.u.qk.q[row * 40 + d] = val;
                        else if (t == 1) W.u.qk.k[row * 40 + d] = val;
                        else             W.vt[d * 72 + row] = val;
                    }
            }
        // no barrier: this wave's own buffers; lgkmcnt orders write->read

        // ---- scores S = q @ k^T  (K=32, one mfma per 16x16 tile) -------
        f32x4 s[4][4];
        {
            bf16x8 aq[4], bkf[4];
#pragma unroll
            for (int mt = 0; mt < 4; ++mt)
                aq[mt] = *(const bf16x8*)(&W.u.qk.q[(16 * mt + cc) * 40 + quad * 8]);
#pragma unroll
            for (int nt = 0; nt < 4; ++nt)
                bkf[nt] = *(const bf16x8*)(&W.u.qk.k[(16 * nt + cc) * 40 + quad * 8]);
            const f32x4 z = (f32x4){0.f, 0.f, 0.f, 0.f};
#pragma unroll
            for (int mt = 0; mt < 4; ++mt)
#pragma unroll
                for (int nt = 0; nt < 4; ++nt)
                    s[mt][nt] = mfma16(aq[mt], bkf[nt], z);
        }

        // ---- softmax (row r in lanes [16*quad .. 16*quad+15]) ----------
        // P overwrites q/k storage; every P value depends on all score
        // fragments, so the overwrite is dataflow-ordered after the reads.
        float linv[4][4];
#pragma unroll
        for (int mt = 0; mt < 4; ++mt)
#pragma unroll
            for (int j = 0; j < 4; ++j) {
                const int r = 16 * mt + 4 * quad + j;
                float vals[4];
#pragma unroll
                for (int nt = 0; nt < 4; ++nt) {
                    const int c = 16 * nt + cc;
                    float sc = s[mt][nt][j] * SCALE;
                    if (r < 49 && c < 49) {
                        int idx = pr[mt * 4 + j] - pc[nt] + 84;
                        sc += (float)tabL[idx * 8 + h] + (float)maskL[r * 49 + c];
                    } else {
                        sc = -1e30f;
                    }
                    vals[nt] = sc;
                }
                float mx = fmaxf(fmaxf(vals[0], vals[1]), fmaxf(vals[2], vals[3]));
                mx = fmaxf(mx, __shfl_xor(mx, 1));
                mx = fmaxf(mx, __shfl_xor(mx, 2));
                mx = fmaxf(mx, __shfl_xor(mx, 4));
                mx = fmaxf(mx, __shfl_xor(mx, 8));
                float sum = 0.f;
#pragma unroll
                for (int nt = 0; nt < 4; ++nt) {
                    float e = __expf(vals[nt] - mx);   // masked cols: exp(-1e30)=0
                    sum += e;
                    W.u.P[r * 72 + 16 * nt + cc] = (bf16)e;
                }
                sum += __shfl_xor(sum, 1);
                sum += __shfl_xor(sum, 2);
                sum += __shfl_xor(sum, 4);
                sum += __shfl_xor(sum, 8);
                linv[mt][j] = 1.0f / sum;
            }
        // no barrier: P/vt are this wave's own; lgkmcnt orders write->read

        // ---- O = P @ v  (K=64 tokens: 2 mfma K-steps) ------------------
        f32x4 o[4][2];
#pragma unroll
        for (int mt = 0; mt < 4; ++mt) {
            o[mt][0] = (f32x4){0.f, 0.f, 0.f, 0.f};
            o[mt][1] = (f32x4){0.f, 0.f, 0.f, 0.f};
        }
#pragma unroll
        for (int kk = 0; kk < 2; ++kk) {
            bf16x8 bvf[2];
#pragma unroll
            for (int nt = 0; nt < 2; ++nt)
                bvf[nt] = *(const bf16x8*)(&W.vt[(16 * nt + cc) * 72 + kk * 32 + quad * 8]);
#pragma unroll
            for (int mt = 0; mt < 4; ++mt) {
                bf16x8 ap = *(const bf16x8*)(&W.u.P[(16 * mt + cc) * 72 + kk * 32 + quad * 8]);
                o[mt][0] = mfma16(ap, bvf[0], o[mt][0]);
                o[mt][1] = mfma16(ap, bvf[1], o[mt][1]);
            }
        }
        // Fence the one non-dataflow-protected hazard: next head's
        // projection ds_writes (q/k/vt) must not pass this head's P/vt
        // ds_reads. "memory" clobber blocks compile-time motion; the
        // waitcnt drains at runtime (~free: MFMAs above already consumed).
        asm volatile("s_waitcnt lgkmcnt(0)" ::: "memory");

        // ---- epilogue: normalize (fp32) + store fp32 -------------------
        float* op = out + (size_t)b * (NTOK * 256) + h * 32;
#pragma unroll
        for (int mt = 0; mt < 4; ++mt)
#pragma unroll
            for (int j = 0; j < 4; ++j) {
                const int r = 16 * mt + 4 * quad + j;
                if (r < 49) {
                    op[(size_t)r * 256 + 0 * 16 + cc] = o[mt][0][j] * linv[mt][j];
                    op[(size_t)r * 256 + 1 * 16 + cc] = o[mt][1][j] * linv[mt][j];
                }
            }
    }
}

// --------------------------------------------------------------------------
extern "C" void kernel_launch(void* const* d_in, const int* in_sizes, int n_in,
                              void* d_out, int out_size, void* d_ws, size_t ws_size,
                              hipStream_t stream) {
    const float* hidden = (const float*)d_in[0];   // [4096,49,256]
    const float* mask   = (const float*)d_in[1];   // [64,49,49]
    const float* wq     = (const float*)d_in[2];   // [256,256]
    const float* bq     = (const float*)d_in[3];   // [256]
    const float* wk     = (const float*)d_in[4];
    const float* bk     = (const float*)d_in[5];
    const float* wv     = (const float*)d_in[6];
    const float* bv     = (const float*)d_in[7];
    const float* tab    = (const float*)d_in[8];   // [169,8]
    float* out = (float*)d_out;
    bf16* pkw = (bf16*)d_ws;                       // 393,216 B of repacked bf16 weights

    repack_w<<<768, 256, 0, stream>>>(wq, wk, wv, pkw);
    swin_attn<<<4096, 128, 0, stream>>>(hidden, mask, bq, bk, bv, tab, pkw, out);
}